// Round 7
// baseline (236.935 us; speedup 1.0000x reference)
//
#include <hip/hip_runtime.h>

// PCEN: x [32, 256, 4096] fp32. EMA over time per row, then
// out = sqrt(x / (m+eps)^0.98 + 2) - sqrt(2).
//
// ROUND 7: row-granularity software pipelining. Evidence from rounds
// 2/5/6: four structurally different schedules (incl. 16-deep burst,
// AGPR-parked row, 32-58% occupancy) ALL land at 83-94us / 2.4 TB/s.
// Theory: every version is a per-wave convoy {load burst -> ~3-4K cy
// silent compute (shuffle scan + 192 trans) -> store burst}; co-resident
// waves run in near-lockstep, so the CU memory pipe idles ~55% of the
// time. Fix = keep the memory pipe busy WITHIN each wave: 4 rows per
// wave, depth-1 rotating pipeline (load row r+1 issued before compute
// of row r; stores of r-1 drain under compute of r). Rows are
// independent scans, so this is free algorithmically.
// Plus: non-temporal stores (out is never re-read; stop it evicting the
// L3-resident input), and the round-6 clobber fence after each load
// burst (prevents load re-materialization, proven VGPR 32->60+).
//
// Scan math per row (verified passing rounds 0-2,5,6): per-lane 4-elem
// local EMA (segment coeff A4=0.975^4), 6-step Hillis-Steele wave scan
// with coeffs A4^(2^d), 16-way ILP across sub-chunks, serial carry
// chain (coeff A256) fused with the epilogue.

typedef float f32x4 __attribute__((ext_vector_type(4)));

constexpr int T_LEN = 4096;
constexpr int LANES = 64;
constexpr int NSUB  = 16;               // sub-chunks of 256 elems (64 x float4)
constexpr int ROWS_PW = 4;              // rows per wave (pipeline length)
constexpr int WAVES_PER_BLK = 4;
constexpr int NTHR  = LANES * WAVES_PER_BLK;

constexpr float EPSF = 1e-6f;
constexpr float SF   = 0.025f;
constexpr float A1F  = 0.975f;

// exact powers of 0.975 via constexpr repeated squaring
constexpr double dA1   = 0.975;
constexpr double dA2   = dA1 * dA1;
constexpr double dA4   = dA2 * dA2;     // per-lane segment coeff (4 steps)
constexpr double dA8   = dA4 * dA4;
constexpr double dA16  = dA8 * dA8;
constexpr double dA32  = dA16 * dA16;
constexpr double dA64  = dA32 * dA32;
constexpr double dA128 = dA64 * dA64;
constexpr double dA256 = dA128 * dA128; // per-sub-chunk coeff (64 lanes x 4)

__global__ __launch_bounds__(NTHR) void pcen_wave_kernel(
    const float* __restrict__ x, float* __restrict__ out, int rows)
{
    const int lane = threadIdx.x & 63;
    const int wave = threadIdx.x >> 6;
    const int wid  = blockIdx.x * WAVES_PER_BLK + wave;
    const int row0 = wid * ROWS_PW;
    if (row0 >= rows) return;

    const float cA4   = (float)dA4;
    const float cA8   = (float)dA8;
    const float cA16  = (float)dA16;
    const float cA32  = (float)dA32;
    const float cA64  = (float)dA64;
    const float cA128 = (float)dA128;
    const float cA256 = (float)dA256;

    // lane-constant carry decay: A4^lane
    float flane = 1.0f;
    if (lane & 1)  flane *= cA4;
    if (lane & 2)  flane *= cA8;
    if (lane & 4)  flane *= cA16;
    if (lane & 8)  flane *= cA32;
    if (lane & 16) flane *= cA64;
    if (lane & 32) flane *= cA128;

    const float SQRT_D = 1.41421356237309515f;  // sqrt(2.0)

    // ---- issue one row's 16 coalesced loads; fence pins them in regs ----
    auto load_row = [&](float4* dst, int r) {
        const float4* p = (const float4*)(x + (long long)r * T_LEN);
#pragma unroll
        for (int s = 0; s < NSUB; ++s) dst[s] = p[s * LANES + lane];
        // loads cannot sink below this point; px cannot be re-read below it
        asm volatile("" ::: "memory");
    };

    // ---- full scan + fused epilogue + NT stores for one row ----
    auto scan_store = [&](const float4* d, int r) {
        float4* po = (float4*)(out + (long long)r * T_LEN);

        // per-lane local 4-elem scans (zero init)
        float Sv[NSUB];
#pragma unroll
        for (int s = 0; s < NSUB; ++s) {
            float m = SF * d[s].x;
            m = fmaf(A1F, m, SF * d[s].y);
            m = fmaf(A1F, m, SF * d[s].z);
            m = fmaf(A1F, m, SF * d[s].w);
            Sv[s] = m;
        }

        // 16 independent wave scans, coeff A4^offset
#pragma unroll
        for (int s = 0; s < NSUB; ++s) {
            float tt;
            tt = __shfl_up(Sv[s], 1,  64); if (lane >= 1)  Sv[s] = fmaf(cA4,   tt, Sv[s]);
            tt = __shfl_up(Sv[s], 2,  64); if (lane >= 2)  Sv[s] = fmaf(cA8,   tt, Sv[s]);
            tt = __shfl_up(Sv[s], 4,  64); if (lane >= 4)  Sv[s] = fmaf(cA16,  tt, Sv[s]);
            tt = __shfl_up(Sv[s], 8,  64); if (lane >= 8)  Sv[s] = fmaf(cA32,  tt, Sv[s]);
            tt = __shfl_up(Sv[s], 16, 64); if (lane >= 16) Sv[s] = fmaf(cA64,  tt, Sv[s]);
            tt = __shfl_up(Sv[s], 32, 64); if (lane >= 32) Sv[s] = fmaf(cA128, tt, Sv[s]);
        }

        // serial carry chain fused with epilogue + non-temporal stores
        float carry = 0.0f;
#pragma unroll
        for (int s = 0; s < NSUB; ++s) {
            float excl = __shfl_up(Sv[s], 1, 64);
            if (lane == 0) excl = 0.0f;
            float last = __shfl(Sv[s], 63, 64);

            float m = fmaf(flane, carry, excl);   // EMA just before lane's segment
            carry   = fmaf(cA256, carry, last);   // EMA at end of this sub-chunk

            float4 v = d[s];
            float4 o;
            m = fmaf(A1F, m, SF * v.x);
            o.x = __builtin_amdgcn_sqrtf(
                      fmaf(v.x, __builtin_amdgcn_exp2f(
                          -0.98f * __builtin_amdgcn_logf(m + EPSF)), 2.0f)) - SQRT_D;
            m = fmaf(A1F, m, SF * v.y);
            o.y = __builtin_amdgcn_sqrtf(
                      fmaf(v.y, __builtin_amdgcn_exp2f(
                          -0.98f * __builtin_amdgcn_logf(m + EPSF)), 2.0f)) - SQRT_D;
            m = fmaf(A1F, m, SF * v.z);
            o.z = __builtin_amdgcn_sqrtf(
                      fmaf(v.z, __builtin_amdgcn_exp2f(
                          -0.98f * __builtin_amdgcn_logf(m + EPSF)), 2.0f)) - SQRT_D;
            m = fmaf(A1F, m, SF * v.w);
            o.w = __builtin_amdgcn_sqrtf(
                      fmaf(v.w, __builtin_amdgcn_exp2f(
                          -0.98f * __builtin_amdgcn_logf(m + EPSF)), 2.0f)) - SQRT_D;

            f32x4 ov = {o.x, o.y, o.z, o.w};
            __builtin_nontemporal_store(ov, (f32x4*)(po + s * LANES + lane));
        }
    };

    float4 bufA[NSUB], bufB[NSUB];

    if (row0 + ROWS_PW <= rows) {
        // depth-1 rotating pipeline over 4 rows:
        // loads of row r+1 are in flight under compute of row r;
        // stores of row r drain under compute of row r+1.
        load_row(bufA, row0);
        load_row(bufB, row0 + 1);
        scan_store(bufA, row0);
        load_row(bufA, row0 + 2);
        scan_store(bufB, row0 + 1);
        load_row(bufB, row0 + 3);
        scan_store(bufA, row0 + 2);
        scan_store(bufB, row0 + 3);
    } else {
        for (int r = row0; r < rows; ++r) {
            load_row(bufA, r);
            scan_store(bufA, r);
        }
    }
}

extern "C" void kernel_launch(void* const* d_in, const int* in_sizes, int n_in,
                              void* d_out, int out_size, void* d_ws, size_t ws_size,
                              hipStream_t stream) {
    const float* x = (const float*)d_in[0];
    float* out = (float*)d_out;
    const int rows = in_sizes[0] / T_LEN;  // 32*256 = 8192
    const int rows_per_blk = ROWS_PW * WAVES_PER_BLK;
    const int blocks = (rows + rows_per_blk - 1) / rows_per_blk;  // 512
    pcen_wave_kernel<<<dim3(blocks), dim3(NTHR), 0, stream>>>(x, out, rows);
}